// Round 12
// baseline (45.456 us; speedup 1.0000x reference)
//
#include <hip/hip_runtime.h>

#define VOCAB 50257
#define EMBED 128
#define NTOK  (64 * 4096)
#define NSLICE 8            // 8 slices x 16 embed dims
#define TV 512              // v per transpose tile
#define TE 16               // e per transpose tile (exactly one slice)

typedef float    f32x4 __attribute__((ext_vector_type(4)));
typedef _Float16 f16x4 __attribute__((ext_vector_type(4)));
typedef _Float16 f16x8 __attribute__((ext_vector_type(8)));

// Pass 1: slice-major fp16 table with bias folded:
//   Wt[s][v][e'] = (half)(W[s*16+e'][v] + bias[s*16+e'])
// Tile 512v x 16e. LDS kept in SOURCE orientation [e][v]:
//  - global->LDS: linear ds_write_b128, conflict-free
//  - LDS->out: column reads (lanes sweep v) -> 2 lanes/bank = free
// Row reads are 2 KB contiguous (vs 256 B before): DRAM-page friendly.
__global__ void transpose_h_kernel(const float* __restrict__ W,
                                   const float* __restrict__ bias,
                                   _Float16* __restrict__ Wt) {
    __shared__ float tile[TE][TV];   // 32 KB
    const int t  = threadIdx.x;
    const int v0 = blockIdx.x * TV;
    const int s  = blockIdx.y;       // slice index
    const int e0 = s * TE;
    const bool full = (v0 + TV <= VOCAB);

    if (full) {
        // 16 rows x 2 KB; 128 f32x4 lanes/row; 2 rows per iter; 8 iters.
#pragma unroll
        for (int it = 0; it < 8; ++it) {
            const int e_loc = it * 2 + (t >> 7);
            const int lv    = t & 127;
            const f32x4 val =
                *(const f32x4*)&W[(size_t)(e0 + e_loc) * VOCAB + v0 + lv * 4];
            *(f32x4*)&tile[e_loc][lv * 4] = val;   // linear b128, no conflicts
        }
    } else {
        // Tail v-block (v0 = 50176, 81 valid): guarded scalar loads.
        for (int e_loc = 0; e_loc < TE; ++e_loc) {
#pragma unroll
            for (int k = 0; k < 2; ++k) {
                const int v_loc = t + k * 256;
                const int v     = v0 + v_loc;
                tile[e_loc][v_loc] =
                    (v < VOCAB) ? W[(size_t)(e0 + e_loc) * VOCAB + v] : 0.0f;
            }
        }
    }
    __syncthreads();

    // Slice bias (uniform addresses -> scalar loads, broadcast).
    float b[TE];
#pragma unroll
    for (int j = 0; j < TE; ++j) b[j] = bias[e0 + j];

    // Readout: 2 v per thread; transpose happens here (conflict-free).
#pragma unroll
    for (int k = 0; k < 2; ++k) {
        const int v_loc = t + k * 256;
        const int v     = v0 + v_loc;
        if (v < VOCAB) {
            f16x8 h0, h1;
#pragma unroll
            for (int j = 0; j < 8; ++j)
                h0[j] = (_Float16)(tile[j][v_loc] + b[j]);
#pragma unroll
            for (int j = 0; j < 8; ++j)
                h1[j] = (_Float16)(tile[8 + j][v_loc] + b[8 + j]);
            _Float16* dst = &Wt[((size_t)s * VOCAB + v) * 16];
            *(f16x8*)dst       = h0;
            *(f16x8*)(dst + 8) = h1;
        }
    }
}

// Pass 2: sliced gather — IDENTICAL to R7/R11 proven path.
__global__ void gather_sliced_kernel(const int* __restrict__ x,
                                     const f16x4* __restrict__ Wt,
                                     f32x4* __restrict__ out) {
    const int bid   = blockIdx.x;
    const int slice = bid & (NSLICE - 1);
    const int tblk  = bid >> 3;
    const int t     = threadIdx.x;
    const int tok   = tblk * 64 + (t >> 2);
    const int q     = t & 3;
    const int idx   = x[tok];
    const f16x4 h = Wt[((size_t)slice * VOCAB + idx) * 4 + q];
    f32x4 r;
    r.x = (float)h[0];
    r.y = (float)h[1];
    r.z = (float)h[2];
    r.w = (float)h[3];
    out[(size_t)tok * 32 + slice * 4 + q] = r;
}

// Fallback (ws too small): exact fp32 strided column gather.
__global__ void direct_kernel(const int* __restrict__ x,
                              const float* __restrict__ W,
                              const float* __restrict__ bias,
                              f32x4* __restrict__ out) {
    const int gid   = blockIdx.x * blockDim.x + threadIdx.x;
    const int token = gid >> 5;
    const int e4    = gid & 31;
    const int idx   = x[token];
    const int e     = e4 * 4;
    f32x4 r;
    r.x = W[(size_t)(e + 0) * VOCAB + idx] + bias[e + 0];
    r.y = W[(size_t)(e + 1) * VOCAB + idx] + bias[e + 1];
    r.z = W[(size_t)(e + 2) * VOCAB + idx] + bias[e + 2];
    r.w = W[(size_t)(e + 3) * VOCAB + idx] + bias[e + 3];
    out[(size_t)token * 32 + e4] = r;
}

extern "C" void kernel_launch(void* const* d_in, const int* in_sizes, int n_in,
                              void* d_out, int out_size, void* d_ws, size_t ws_size,
                              hipStream_t stream) {
    const int*   x    = (const int*)d_in[0];
    const float* W    = (const float*)d_in[1];
    const float* bias = (const float*)d_in[2];

    const size_t wt_bytes = (size_t)VOCAB * EMBED * sizeof(_Float16); // 12.9 MB

    if (ws_size >= wt_bytes) {
        _Float16* Wt = (_Float16*)d_ws;
        dim3 tgrid((VOCAB + TV - 1) / TV, NSLICE);   // 99 x 8 = 792 blocks
        transpose_h_kernel<<<tgrid, 256, 0, stream>>>(W, bias, Wt);

        const int gblocks = (NTOK / 64) * NSLICE;    // 32768
        gather_sliced_kernel<<<gblocks, 256, 0, stream>>>(x, (const f16x4*)Wt,
                                                          (f32x4*)d_out);
    } else {
        const int dblocks = (NTOK * 32) / 256;
        direct_kernel<<<dblocks, 256, 0, stream>>>(x, W, bias, (f32x4*)d_out);
    }
}

// Round 13
// 44.845 us; speedup vs baseline: 1.0136x; 1.0136x over previous
//
#include <hip/hip_runtime.h>

#define VOCAB 50257
#define EMBED 128
#define NTOK  (64 * 4096)
#define NSLICE 8            // 8 slices x 16 embed dims
#define GBLOCKS 2048        // persistent gather: 8 blocks/CU x 256 CU
#define NVB   (NTOK / 64 * NSLICE)   // 32768 work items
#define ITEMS (NVB / GBLOCKS)        // 16 per block

typedef float    f32x4 __attribute__((ext_vector_type(4)));
typedef _Float16 f16x4 __attribute__((ext_vector_type(4)));
typedef _Float16 f16x8 __attribute__((ext_vector_type(8)));

// Pass 1: slice-major fp16 table with bias folded (R11 champion version):
//   Wt[s][v][e'] = (half)(W[s*16+e'][v] + bias[s*16+e'])
// Tile 64v x 32e, grid=(786,4), block=256, LDS 8.4 KB.
__global__ void transpose_h_kernel(const float* __restrict__ W,
                                   const float* __restrict__ bias,
                                   _Float16* __restrict__ Wt) {
    __shared__ float tile[64][33];   // [v_loc][e_loc], +1 pad
    const int t  = threadIdx.x;
    const int v0 = blockIdx.x * 64;
    const int e0 = blockIdx.y * 32;
    const bool full = (v0 + 64 <= VOCAB);

    if (full) {
#pragma unroll
        for (int it = 0; it < 2; ++it) {
            const int e_loc = (t >> 4) + it * 16;
            const int c4    = (t & 15) * 4;
            f32x4 val = *(const f32x4*)&W[(size_t)(e0 + e_loc) * VOCAB + v0 + c4];
            tile[c4 + 0][e_loc] = val.x;
            tile[c4 + 1][e_loc] = val.y;
            tile[c4 + 2][e_loc] = val.z;
            tile[c4 + 3][e_loc] = val.w;
        }
    } else {
#pragma unroll
        for (int it = 0; it < 8; ++it) {
            const int e_loc = (t >> 6) + it * 4;
            const int c     = t & 63;
            const int v     = v0 + c;
            tile[c][e_loc] = (v < VOCAB) ? W[(size_t)(e0 + e_loc) * VOCAB + v]
                                         : 0.0f;
        }
    }
    __syncthreads();

    const int v_loc = t >> 2;
    const int eo    = (t & 3) * 8;
    const int eg    = e0 + eo;
    const int s     = eg >> 4;
    const int ep    = eg & 15;
    const int v     = v0 + v_loc;
    if (v < VOCAB) {
        const f32x4 ba = *(const f32x4*)&bias[eg];
        const f32x4 bb = *(const f32x4*)&bias[eg + 4];
        f16x8 h;
        h[0] = (_Float16)(tile[v_loc][eo + 0] + ba.x);
        h[1] = (_Float16)(tile[v_loc][eo + 1] + ba.y);
        h[2] = (_Float16)(tile[v_loc][eo + 2] + ba.z);
        h[3] = (_Float16)(tile[v_loc][eo + 3] + ba.w);
        h[4] = (_Float16)(tile[v_loc][eo + 4] + bb.x);
        h[5] = (_Float16)(tile[v_loc][eo + 5] + bb.y);
        h[6] = (_Float16)(tile[v_loc][eo + 6] + bb.z);
        h[7] = (_Float16)(tile[v_loc][eo + 7] + bb.w);
        *(f16x8*)&Wt[((size_t)s * VOCAB + v) * 16 + ep] = h;
    }
}

// Pass 2: PERSISTENT sliced gather. 2048 blocks (8/CU), slice fixed per
// block (bid&7; stride 2048 ≡ 0 mod 8), 16 work items each. Same memory
// pattern as the proven R7/R11 gather, 16x fewer dispatches.
__global__ void gather_persist_kernel(const int* __restrict__ x,
                                      const f16x4* __restrict__ Wt,
                                      f32x4* __restrict__ out) {
    const int bid   = blockIdx.x;
    const int slice = bid & (NSLICE - 1);
    const int t     = threadIdx.x;
    const int lq    = t & 3;                 // f16x4 quad within slice
    const int lt    = t >> 2;                // token 0..63 within item
    const f16x4* Wts = Wt + (size_t)slice * VOCAB * 4;
    const int tb0   = bid >> 3;

#pragma unroll 4
    for (int k = 0; k < ITEMS; ++k) {
        const int tblk = tb0 + k * (GBLOCKS / NSLICE);   // +256 per item
        const int tok  = tblk * 64 + lt;
        const int idx  = x[tok];
        const f16x4 h  = Wts[(size_t)idx * 4 + lq];
        f32x4 r;
        r.x = (float)h[0];
        r.y = (float)h[1];
        r.z = (float)h[2];
        r.w = (float)h[3];
        out[(size_t)tok * 32 + slice * 4 + lq] = r;  // 4-lane group = 64B line
    }
}

// Fallback (ws too small): exact fp32 strided column gather.
__global__ void direct_kernel(const int* __restrict__ x,
                              const float* __restrict__ W,
                              const float* __restrict__ bias,
                              f32x4* __restrict__ out) {
    const int gid   = blockIdx.x * blockDim.x + threadIdx.x;
    const int token = gid >> 5;
    const int e4    = gid & 31;
    const int idx   = x[token];
    const int e     = e4 * 4;
    f32x4 r;
    r.x = W[(size_t)(e + 0) * VOCAB + idx] + bias[e + 0];
    r.y = W[(size_t)(e + 1) * VOCAB + idx] + bias[e + 1];
    r.z = W[(size_t)(e + 2) * VOCAB + idx] + bias[e + 2];
    r.w = W[(size_t)(e + 3) * VOCAB + idx] + bias[e + 3];
    out[(size_t)token * 32 + e4] = r;
}

extern "C" void kernel_launch(void* const* d_in, const int* in_sizes, int n_in,
                              void* d_out, int out_size, void* d_ws, size_t ws_size,
                              hipStream_t stream) {
    const int*   x    = (const int*)d_in[0];
    const float* W    = (const float*)d_in[1];
    const float* bias = (const float*)d_in[2];

    const size_t wt_bytes = (size_t)VOCAB * EMBED * sizeof(_Float16); // 12.9 MB

    if (ws_size >= wt_bytes) {
        _Float16* Wt = (_Float16*)d_ws;
        dim3 tgrid((VOCAB + 63) / 64, 4);   // 786 x 4 = 3144 blocks
        transpose_h_kernel<<<tgrid, 256, 0, stream>>>(W, bias, Wt);

        gather_persist_kernel<<<GBLOCKS, 256, 0, stream>>>(x, (const f16x4*)Wt,
                                                           (f32x4*)d_out);
    } else {
        const int dblocks = (NTOK * 32) / 256;
        direct_kernel<<<dblocks, 256, 0, stream>>>(x, W, bias, (f32x4*)d_out);
    }
}